// Round 9
// baseline (85.570 us; speedup 1.0000x reference)
//
#include <hip/hip_runtime.h>
#include <stdint.h>

// GAT: N=4096, F_in=512, H=8, F_out=64.
// exp(lrelu(s_i+d_j)) = max(e^{s_i} e^{d_j}, e^{0.2 s_i} e^{0.2 d_j})  (exact)
// Round 9: gat waves cover 32 rows (dual-af per B-read) -> LDS B-traffic and
// per-tile overhead halve. proj gets 2-way K-split + flat grid (17 waves/CU).

#define NN 4096
#define FIN 512
#define NH 8
#define FO 64

typedef _Float16 f16x8 __attribute__((ext_vector_type(8)));
typedef _Float16 f16x2 __attribute__((ext_vector_type(2)));
typedef __attribute__((ext_vector_type(4))) float f32x4;

union H8 { f16x8 v; f16x2 p[4]; unsigned u[4]; };
union U2 { unsigned u; f16x2 v; };

#define GLOAD_LDS16(g, l)                                                          \
  __builtin_amdgcn_global_load_lds((__attribute__((address_space(1))) const void*)(g), \
                                   (__attribute__((address_space(3))) void*)(l), 16, 0, 0)
#define GLOAD_LDS4(g, l)                                                           \
  __builtin_amdgcn_global_load_lds((__attribute__((address_space(1))) const void*)(g), \
                                   (__attribute__((address_space(3))) void*)(l), 4, 0, 0)

__device__ __forceinline__ unsigned short f2h(float f) {
  _Float16 h = (_Float16)f;               // RNE
  return __builtin_bit_cast(unsigned short, h);
}

// ---------------- prep: adj->bitsT, X->fp16, W->WbT(fp16), wa = W^T a ----------------
__global__ __launch_bounds__(256) void prep_kernel(
    const float* __restrict__ X, const int* __restrict__ adj, const float* __restrict__ W,
    const float* __restrict__ a,
    unsigned short* __restrict__ Xh, unsigned short* __restrict__ WbT,
    unsigned* __restrict__ adjbitsT, unsigned short* __restrict__ WAh) {
  int bid = blockIdx.x, tid = threadIdx.x;
  if (bid < 2048) {                       // adj -> bit words, transposed [jt][r]
    int item = bid * 256 + tid;           // item = jt*4096 + r
    int jt = item >> 12, r = item & 4095;
    const int* p = adj + (size_t)r * NN + jt * 32;
    unsigned bits = 0;
#pragma unroll
    for (int b = 0; b < 32; b += 4) {
      int4 v = *(const int4*)(p + b);
      bits |= (unsigned)(v.x & 1) << b;
      bits |= (unsigned)(v.y & 1) << (b + 1);
      bits |= (unsigned)(v.z & 1) << (b + 2);
      bits |= (unsigned)(v.w & 1) << (b + 3);
    }
    adjbitsT[item] = bits;
  } else if (bid < 4096) {                // X -> fp16
    int item = (bid - 2048) * 256 + tid;
    float4 v = ((const float4*)X)[item];
    ushort4 o;
    o.x = f2h(v.x); o.y = f2h(v.y); o.z = f2h(v.z); o.w = f2h(v.w);
    ((ushort4*)Xh)[item] = o;
  } else if (bid < 5120) {                // W[h][k][o] -> WbT[h][o][k] fp16
    int item = (bid - 4096) * 256 + tid;
    int h = item >> 15, rem = item & 32767, o = rem >> 9, k = rem & 511;
    WbT[item] = f2h(W[h * (FIN * FO) + k * FO + o]);
  } else {                                // wa[t][k] = sum_o W[h][k][o] * a[h][which*64+o]
    int item = (bid - 5120) * 256 + tid;  // 8192 items: t = h*2+which, k
    int h = item >> 10, which = (item >> 9) & 1, k = item & 511;
    const float4* wp = (const float4*)(W + ((size_t)h * FIN + k) * FO);
    const float4* ap = (const float4*)(a + h * 128 + which * 64);
    float s = 0.f;
#pragma unroll
    for (int o4 = 0; o4 < 16; ++o4) {
      float4 w4 = wp[o4], a4 = ap[o4];
      s += w4.x * a4.x + w4.y * a4.y + w4.z * a4.z + w4.w * a4.w;
    }
    WAh[(h * 2 + which) * FIN + k] = f2h(s);
  }
}

// ---------------- proj (+sd): 2-way K-split jobs; sd blocks at bx>=512 -------------
// D layout (16x16x32): col = lane&15, row = (lane>>4)*4 + reg   [m89]
__global__ __launch_bounds__(512, 4) void proj_sd_kernel(
    const unsigned short* __restrict__ Xh, const unsigned short* __restrict__ WbT,
    const unsigned short* __restrict__ WAh,
    unsigned short* __restrict__ Whfrag, float2* __restrict__ ABf,
    unsigned short* __restrict__ E1h, unsigned short* __restrict__ E2h) {
  __shared__ float red[4 * 64 * 20];      // 20KB partial store (jobs x lanes x 16used/20)
  int lane = threadIdx.x & 63, wave = threadIdx.x >> 6;
  int row16 = lane & 15, grp = lane >> 4;
  int bx = blockIdx.x;
  if (bx >= 512) {                        // sd: [s,d]x8 = X @ WA  (16 cols, K=512)
    int i0 = ((bx - 512) * 8 + wave) * 16;
    f32x4 acc = {0, 0, 0, 0};
    const unsigned short* xb = Xh + (size_t)(i0 + row16) * FIN + grp * 8;
    const unsigned short* wb = WAh + row16 * FIN + grp * 8;
#pragma unroll
    for (int k0 = 0; k0 < FIN; k0 += 32)
      acc = __builtin_amdgcn_mfma_f32_16x16x32_f16(*(const f16x8*)(xb + k0),
                                                   *(const f16x8*)(wb + k0), acc, 0, 0, 0);
    int hh = row16 >> 1;
#pragma unroll
    for (int reg = 0; reg < 4; ++reg) {
      int rr = i0 + grp * 4 + reg;
      float v = acc[reg];
      if (row16 & 1) {                    // d -> col tables fp16
        E1h[hh * NN + rr] = f2h(__expf(v));
        E2h[hh * NN + rr] = f2h(__expf(0.2f * v));
      } else {                            // s -> row tables f32
        ABf[hh * NN + rr] = make_float2(__expf(v), __expf(0.2f * v));
      }
    }
    return;
  }
  int kh = wave >> 2, jb = wave & 3;
  int job = bx * 4 + jb;                  // 2048 jobs = 256 rowtiles x 8 heads
  int h = job & 7, rt = job >> 3;
  int i0 = rt * 16;
  f32x4 acc[4] = {{0,0,0,0},{0,0,0,0},{0,0,0,0},{0,0,0,0}};
  const unsigned short* xb = Xh + (size_t)(i0 + row16) * FIN + kh * 256 + grp * 8;
  const unsigned short* wb = WbT + h * (FO * FIN) + row16 * FIN + kh * 256 + grp * 8;
#pragma unroll
  for (int k0 = 0; k0 < 256; k0 += 32) {
    f16x8 af = *(const f16x8*)(xb + k0);
#pragma unroll
    for (int cb = 0; cb < 4; ++cb)
      acc[cb] = __builtin_amdgcn_mfma_f32_16x16x32_f16(
          af, *(const f16x8*)(wb + cb * 16 * FIN + k0), acc[cb], 0, 0, 0);
  }
  if (kh == 1) {
    float* q = red + (jb * 64 + lane) * 20;
#pragma unroll
    for (int cb = 0; cb < 4; ++cb) *(f32x4*)(q + cb * 4) = acc[cb];
  }
  __syncthreads();
  if (kh == 0) {
    const float* q = red + (jb * 64 + lane) * 20;
#pragma unroll
    for (int cb = 0; cb < 4; ++cb) acc[cb] += *(const f32x4*)(q + cb * 4);
    // Whfrag[h][jt][cb][l][e] = Wh[jt*32 + (l>>4)*8 + e][cb*16 + (l&15)]
    int jt = i0 >> 5;
    int kk0 = (i0 & 31) + grp * 4;
    int tl = (kk0 >> 3) * 16 + row16;
    int e0 = kk0 & 7;
#pragma unroll
    for (int cb = 0; cb < 4; ++cb) {
      ushort4 pk;
      pk.x = f2h(acc[cb][0]); pk.y = f2h(acc[cb][1]);
      pk.z = f2h(acc[cb][2]); pk.w = f2h(acc[cb][3]);
      *(ushort4*)(Whfrag + (((size_t)h * 128 + jt) * 4 + cb) * 512 + tl * 8 + e0) = pk;
    }
  }
}

// ---------------- gat: 2-phase LDS pipeline, 32-row waves (dual af), 4 jseg --------
// SEG per (jseg,buf): [B 4096 | E1 64 | E2 64 | adj 128] = 4352 -> 4608; x8 = 36 KB
#define SEGB 4608
#define E_OFF 4096
#define A_OFF 4224

__global__ __launch_bounds__(256, 4) void gat_kernel(
    const unsigned* __restrict__ adjbitsT, const unsigned short* __restrict__ Whfrag,
    const float2* __restrict__ ABf, const unsigned short* __restrict__ E1h,
    const unsigned short* __restrict__ E2h, float* __restrict__ out) {
  __shared__ __align__(16) char lds[8 * SEGB];
  int h = blockIdx.y;
  int lane = threadIdx.x & 63, jseg = threadIdx.x >> 6;
  int row16 = lane & 15, grp = lane >> 4;
  int r0 = blockIdx.x * 32;
  float2 abL = ABf[h * NN + r0 + row16];
  float2 abH = ABf[h * NN + r0 + 16 + row16];
  _Float16 aL = (_Float16)(0.5f * abL.x), bL = (_Float16)(0.5f * abL.y);
  _Float16 aH = (_Float16)(0.5f * abH.x), bH = (_Float16)(0.5f * abH.y);
  f16x2 AhL = {aL, aL}, BhL = {bL, bL}, AhH = {aH, aH}, BhH = {bH, bH};

  H8 ones;
#pragma unroll
  for (int k = 0; k < 4; ++k) ones.u[k] = 0x3C003C00u;   // fp16 1.0 pairs

  const unsigned short* wsrc =
      Whfrag + (size_t)h * 262144 + (size_t)jseg * 32 * 2048 + lane * 8;
  const unsigned short* esrc =
      ((lane & 4) ? E2h : E1h) + h * NN + jseg * 1024 + (lane & 3) * 8;
  const unsigned* asrc = adjbitsT + (size_t)(jseg * 32) * NN + r0 + lane;

  f32x4 l0 = {0,0,0,0}, l1 = {0,0,0,0}, l2 = {0,0,0,0}, ld = {0,0,0,0}, lden = {0,0,0,0};
  f32x4 h0 = {0,0,0,0}, h1 = {0,0,0,0}, h2 = {0,0,0,0}, hd = {0,0,0,0}, hden = {0,0,0,0};

  char* seg0 = lds + (jseg * 2 + 0) * SEGB;
  char* seg1 = lds + (jseg * 2 + 1) * SEGB;

  auto stage = [&](char* seg, int p) {     // stage tile (jseg*32+p) into seg
    const unsigned short* bs = wsrc + (size_t)p * 2048;
    GLOAD_LDS16(bs, seg);
    GLOAD_LDS16(bs + 512, seg + 1024);
    GLOAD_LDS16(bs + 1024, seg + 2048);
    GLOAD_LDS16(bs + 1536, seg + 3072);
    if (lane < 32) GLOAD_LDS4(asrc + (size_t)p * NN, seg + A_OFF);
    if (lane < 8)  GLOAD_LDS16(esrc + p * 32, seg + E_OFF);
  };

  auto compute = [&](const char* seg) {
    unsigned bwL = *(const unsigned*)(seg + A_OFF + row16 * 4);
    unsigned bwH = *(const unsigned*)(seg + A_OFF + 64 + row16 * 4);
    unsigned bbL = (bwL >> (grp * 8)) & 0xffu;
    unsigned bbH = (bwH >> (grp * 8)) & 0xffu;
    unsigned tL = bbL | (bbL << 15);       // bit k at {k, k+15}
    unsigned tH = bbH | (bbH << 15);
    H8 e1, e2;
    e1.v = *(const f16x8*)(seg + E_OFF + grp * 16);
    e2.v = *(const f16x8*)(seg + E_OFF + 64 + grp * 16);
    const char* bp = seg + lane * 16;
    f16x8 b0 = *(const f16x8*)(bp);
    f16x8 b1 = *(const f16x8*)(bp + 1024);
    f16x8 b2 = *(const f16x8*)(bp + 2048);
    f16x8 b3 = *(const f16x8*)(bp + 3072);
    H8 afL, afH;
#pragma unroll
    for (int k = 0; k < 4; ++k) {
      f16x2 mxL = __builtin_elementwise_max(AhL * e1.p[k], BhL * e2.p[k]);
      f16x2 mxH = __builtin_elementwise_max(AhH * e1.p[k], BhH * e2.p[k]);
      U2 mL, mH;                           // halves: bit2k->pos14, bit2k+1->pos30 (fp16 2.0)
      mL.u = (tL << (14 - 2 * k)) & 0x40004000u;
      mH.u = (tH << (14 - 2 * k)) & 0x40004000u;
      afL.p[k] = mxL * mL.v;
      afH.p[k] = mxH * mH.v;
    }
    l0   = __builtin_amdgcn_mfma_f32_16x16x32_f16(afL.v, b0, l0, 0, 0, 0);
    l1   = __builtin_amdgcn_mfma_f32_16x16x32_f16(afL.v, b1, l1, 0, 0, 0);
    l2   = __builtin_amdgcn_mfma_f32_16x16x32_f16(afL.v, b2, l2, 0, 0, 0);
    ld   = __builtin_amdgcn_mfma_f32_16x16x32_f16(afL.v, b3, ld, 0, 0, 0);
    lden = __builtin_amdgcn_mfma_f32_16x16x32_f16(afL.v, ones.v, lden, 0, 0, 0);
    h0   = __builtin_amdgcn_mfma_f32_16x16x32_f16(afH.v, b0, h0, 0, 0, 0);
    h1   = __builtin_amdgcn_mfma_f32_16x16x32_f16(afH.v, b1, h1, 0, 0, 0);
    h2   = __builtin_amdgcn_mfma_f32_16x16x32_f16(afH.v, b2, h2, 0, 0, 0);
    hd   = __builtin_amdgcn_mfma_f32_16x16x32_f16(afH.v, b3, hd, 0, 0, 0);
    hden = __builtin_amdgcn_mfma_f32_16x16x32_f16(afH.v, ones.v, hden, 0, 0, 0);
  };

  stage(seg0, 0);
  __syncthreads();
#pragma unroll 1
  for (int p2 = 0; p2 < 16; ++p2) {
    stage(seg1, 2 * p2 + 1);
    compute(seg0);
    __syncthreads();
    if (p2 < 15) stage(seg0, 2 * p2 + 2);
    compute(seg1);
    __syncthreads();
  }

  // ---- cross-jseg reduction (reuse LDS, 30720 B) + normalize + store ----
  float* red = (float*)lds;
  if (jseg != 0) {
    float* q = red + ((jseg - 1) * 64 + lane) * 40;
    *(f32x4*)(q +  0) = l0;  *(f32x4*)(q +  4) = l1;
    *(f32x4*)(q +  8) = l2;  *(f32x4*)(q + 12) = ld;
    *(f32x4*)(q + 16) = lden;
    *(f32x4*)(q + 20) = h0;  *(f32x4*)(q + 24) = h1;
    *(f32x4*)(q + 28) = h2;  *(f32x4*)(q + 32) = hd;
    *(f32x4*)(q + 36) = hden;
  }
  __syncthreads();
  if (jseg == 0) {
#pragma unroll
    for (int s = 0; s < 3; ++s) {
      const float* q = red + (s * 64 + lane) * 40;
      l0   += *(const f32x4*)(q +  0);  l1   += *(const f32x4*)(q +  4);
      l2   += *(const f32x4*)(q +  8);  ld   += *(const f32x4*)(q + 12);
      lden += *(const f32x4*)(q + 16);
      h0   += *(const f32x4*)(q + 20);  h1   += *(const f32x4*)(q + 24);
      h2   += *(const f32x4*)(q + 28);  hd   += *(const f32x4*)(q + 32);
      hden += *(const f32x4*)(q + 36);
    }
#pragma unroll
    for (int reg = 0; reg < 4; ++reg) {
      float invL = 1.0f / lden[reg];
      float invH = 1.0f / hden[reg];
      int rowL = r0 + grp * 4 + reg;
      int rowH = r0 + 16 + grp * 4 + reg;
      float* opL = out + (size_t)rowL * (NH * FO) + h * FO + row16;
      float* opH = out + (size_t)rowH * (NH * FO) + h * FO + row16;
      opL[0]  = l0[reg] * invL;  opL[16] = l1[reg] * invL;
      opL[32] = l2[reg] * invL;  opL[48] = ld[reg] * invL;
      opH[0]  = h0[reg] * invH;  opH[16] = h1[reg] * invH;
      opH[32] = h2[reg] * invH;  opH[48] = hd[reg] * invH;
    }
  }
}

extern "C" void kernel_launch(void* const* d_in, const int* in_sizes, int n_in,
                              void* d_out, int out_size, void* d_ws, size_t ws_size,
                              hipStream_t stream) {
  const float* X  = (const float*)d_in[0];
  const int* adj  = (const int*)d_in[1];
  const float* W  = (const float*)d_in[2];
  const float* a  = (const float*)d_in[3];
  float* out = (float*)d_out;
  char* ws = (char*)d_ws;

  unsigned short* Xh     = (unsigned short*)(ws + 0);          // 4 MB
  unsigned short* WbT    = (unsigned short*)(ws + 4194304);    // 512 KB
  unsigned* adjbitsT     = (unsigned*)(ws + 4718592);          // 2 MB
  unsigned short* Whfrag = (unsigned short*)(ws + 6815744);    // 4 MB
  unsigned short* WAh    = (unsigned short*)(ws + 11010048);   // 16 KB
  float2* ABf            = (float2*)(ws + 11026432);           // 256 KB
  unsigned short* E1h    = (unsigned short*)(ws + 11288576);   // 64 KB
  unsigned short* E2h    = (unsigned short*)(ws + 11354112);   // 64 KB (total ~11.4 MB)

  prep_kernel<<<5152, 256, 0, stream>>>(X, adj, W, a, Xh, WbT, adjbitsT, WAh);
  proj_sd_kernel<<<544, 512, 0, stream>>>(Xh, WbT, WAh, Whfrag, ABf, E1h, E2h);
  gat_kernel<<<dim3(128, 8), 256, 0, stream>>>(adjbitsT, Whfrag, ABf, E1h, E2h, out);
}

// Round 11
// 79.769 us; speedup vs baseline: 1.0727x; 1.0727x over previous
//
#include <hip/hip_runtime.h>
#include <stdint.h>

// GAT: N=4096, F_in=512, H=8, F_out=64.
// P_ij = exp(lrelu(s_i+d_j))·adj = A_i·max(E1_j, R_i·E2_j)·adj with R_i=e^{-0.8 s_i};
// A_i cancels in softmax -> af = max(E1_j/2, R_i·E2_j/2)·(2·bit)  (tables pre-halved,
// mask bit<<14 = fp16 2.0). Round 11: round-10 fixed — sd grid 544 (was 576: OOB
// blocks corrupted E-tables with Inf -> NaN). Drop-A algebra, 64-row blocks,
// coalesced W-transpose reads.

#define NN 4096
#define FIN 512
#define NH 8
#define FO 64

typedef _Float16 f16x8 __attribute__((ext_vector_type(8)));
typedef _Float16 f16x2 __attribute__((ext_vector_type(2)));
typedef __attribute__((ext_vector_type(4))) float f32x4;

union H8 { f16x8 v; f16x2 p[4]; unsigned u[4]; };
union U2 { unsigned u; f16x2 v; };

#define GLOAD_LDS16(g, l)                                                          \
  __builtin_amdgcn_global_load_lds((__attribute__((address_space(1))) const void*)(g), \
                                   (__attribute__((address_space(3))) void*)(l), 16, 0, 0)
#define GLOAD_LDS4(g, l)                                                           \
  __builtin_amdgcn_global_load_lds((__attribute__((address_space(1))) const void*)(g), \
                                   (__attribute__((address_space(3))) void*)(l), 4, 0, 0)

__device__ __forceinline__ unsigned short f2h(float f) {
  _Float16 h = (_Float16)f;               // RNE
  return __builtin_bit_cast(unsigned short, h);
}

// ---------------- prep: adj->bitsT, X->fp16, W->WbT(fp16), wa = W^T a ----------------
__global__ __launch_bounds__(256) void prep_kernel(
    const float* __restrict__ X, const int* __restrict__ adj, const float* __restrict__ W,
    const float* __restrict__ a,
    unsigned short* __restrict__ Xh, unsigned short* __restrict__ WbT,
    unsigned* __restrict__ adjbitsT, unsigned short* __restrict__ WAh) {
  int bid = blockIdx.x, tid = threadIdx.x;
  if (bid < 2048) {                       // adj -> bit words, transposed [jt][r]
    int item = bid * 256 + tid;           // item = jt*4096 + r
    int jt = item >> 12, r = item & 4095;
    const int* p = adj + (size_t)r * NN + jt * 32;
    unsigned bits = 0;
#pragma unroll
    for (int b = 0; b < 32; b += 4) {
      int4 v = *(const int4*)(p + b);
      bits |= (unsigned)(v.x & 1) << b;
      bits |= (unsigned)(v.y & 1) << (b + 1);
      bits |= (unsigned)(v.z & 1) << (b + 2);
      bits |= (unsigned)(v.w & 1) << (b + 3);
    }
    adjbitsT[item] = bits;
  } else if (bid < 4096) {                // X -> fp16
    int item = (bid - 2048) * 256 + tid;
    float4 v = ((const float4*)X)[item];
    ushort4 o;
    o.x = f2h(v.x); o.y = f2h(v.y); o.z = f2h(v.z); o.w = f2h(v.w);
    ((ushort4*)Xh)[item] = o;
  } else if (bid < 5120) {                // W[h][k][o] -> WbT[h][o][k], coalesced READ
    int item = (bid - 4096) * 256 + tid;  // item = (h,k,o): wave reads 256B segment
    int o = item & 63, k = (item >> 6) & 511, h = item >> 15;
    WbT[h * 32768 + o * 512 + k] = f2h(W[h * 32768 + k * 64 + o]);
  } else {                                // wa[t][k] = sum_o W[h][k][o] * a[h][which*64+o]
    int item = (bid - 5120) * 256 + tid;  // 8192 items: t = h*2+which, k
    int h = item >> 10, which = (item >> 9) & 1, k = item & 511;
    const float4* wp = (const float4*)(W + ((size_t)h * FIN + k) * FO);
    const float4* ap = (const float4*)(a + h * 128 + which * 64);
    float s = 0.f;
#pragma unroll
    for (int o4 = 0; o4 < 16; ++o4) {
      float4 w4 = wp[o4], a4 = ap[o4];
      s += w4.x * a4.x + w4.y * a4.y + w4.z * a4.z + w4.w * a4.w;
    }
    WAh[(h * 2 + which) * FIN + k] = f2h(s);
  }
}

// ---------------- proj (+sd): 2-way K-split jobs; sd blocks at bx>=512 -------------
// D layout (16x16x32): col = lane&15, row = (lane>>4)*4 + reg   [m89]
__global__ __launch_bounds__(512, 4) void proj_sd_kernel(
    const unsigned short* __restrict__ Xh, const unsigned short* __restrict__ WbT,
    const unsigned short* __restrict__ WAh,
    unsigned short* __restrict__ Whfrag, float* __restrict__ Rf,
    unsigned short* __restrict__ E1h, unsigned short* __restrict__ E2h) {
  __shared__ float red[4 * 64 * 20];      // 20KB partial store
  int lane = threadIdx.x & 63, wave = threadIdx.x >> 6;
  int row16 = lane & 15, grp = lane >> 4;
  int bx = blockIdx.x;
  if (bx >= 512) {                        // sd: [s,d]x8 = X @ WA  (16 cols, K=512)
    int i0 = ((bx - 512) * 8 + wave) * 16;
    if (i0 >= NN) return;                 // guard (32 sd blocks cover all rows)
    f32x4 acc = {0, 0, 0, 0};
    const unsigned short* xb = Xh + (size_t)(i0 + row16) * FIN + grp * 8;
    const unsigned short* wb = WAh + row16 * FIN + grp * 8;
#pragma unroll
    for (int k0 = 0; k0 < FIN; k0 += 32)
      acc = __builtin_amdgcn_mfma_f32_16x16x32_f16(*(const f16x8*)(xb + k0),
                                                   *(const f16x8*)(wb + k0), acc, 0, 0, 0);
    int hh = row16 >> 1;
#pragma unroll
    for (int reg = 0; reg < 4; ++reg) {
      int rr = i0 + grp * 4 + reg;
      float v = acc[reg];
      if (row16 & 1) {                    // d -> col tables fp16, PRE-HALVED
        E1h[hh * NN + rr] = f2h(0.5f * __expf(v));
        E2h[hh * NN + rr] = f2h(0.5f * __expf(0.2f * v));
      } else {                            // s -> row table R = e^{-0.8 s}
        Rf[hh * NN + rr] = __expf(-0.8f * v);
      }
    }
    return;
  }
  int kh = wave >> 2, jb = wave & 3;
  int job = bx * 4 + jb;                  // 2048 jobs = 256 rowtiles x 8 heads
  int h = job & 7, rt = job >> 3;
  int i0 = rt * 16;
  f32x4 acc[4] = {{0,0,0,0},{0,0,0,0},{0,0,0,0},{0,0,0,0}};
  const unsigned short* xb = Xh + (size_t)(i0 + row16) * FIN + kh * 256 + grp * 8;
  const unsigned short* wb = WbT + h * (FO * FIN) + row16 * FIN + kh * 256 + grp * 8;
#pragma unroll
  for (int k0 = 0; k0 < 256; k0 += 32) {
    f16x8 af = *(const f16x8*)(xb + k0);
#pragma unroll
    for (int cb = 0; cb < 4; ++cb)
      acc[cb] = __builtin_amdgcn_mfma_f32_16x16x32_f16(
          af, *(const f16x8*)(wb + cb * 16 * FIN + k0), acc[cb], 0, 0, 0);
  }
  if (kh == 1) {
    float* q = red + (jb * 64 + lane) * 20;
#pragma unroll
    for (int cb = 0; cb < 4; ++cb) *(f32x4*)(q + cb * 4) = acc[cb];
  }
  __syncthreads();
  if (kh == 0) {
    const float* q = red + (jb * 64 + lane) * 20;
#pragma unroll
    for (int cb = 0; cb < 4; ++cb) acc[cb] += *(const f32x4*)(q + cb * 4);
    // Whfrag[h][jt][cb][l][e] = Wh[jt*32 + (l>>4)*8 + e][cb*16 + (l&15)]
    int jt = i0 >> 5;
    int kk0 = (i0 & 31) + grp * 4;
    int tl = (kk0 >> 3) * 16 + row16;
    int e0 = kk0 & 7;
#pragma unroll
    for (int cb = 0; cb < 4; ++cb) {
      ushort4 pk;
      pk.x = f2h(acc[cb][0]); pk.y = f2h(acc[cb][1]);
      pk.z = f2h(acc[cb][2]); pk.w = f2h(acc[cb][3]);
      *(ushort4*)(Whfrag + (((size_t)h * 128 + jt) * 4 + cb) * 512 + tl * 8 + e0) = pk;
    }
  }
}

// ---------------- gat: 2-phase LDS pipeline, 64-row blocks (2rt x 4jseg) ----------
// SEG per (jseg,buf): [B 4096 | E1 64 | E2 64 | adj 256] = 4480 -> 4608; x8 = 36 KB
// red region (end of kernel) overlays: 6 x 64 x 40 f32 = 61440 B total LDS.
#define SEGB 4608
#define E_OFF 4096
#define A_OFF 4224

__global__ __launch_bounds__(512, 4) void gat_kernel(
    const unsigned* __restrict__ adjbitsT, const unsigned short* __restrict__ Whfrag,
    const float* __restrict__ Rf, const unsigned short* __restrict__ E1h,
    const unsigned short* __restrict__ E2h, float* __restrict__ out) {
  __shared__ __align__(16) char lds[61440];
  int h = blockIdx.y;
  int lane = threadIdx.x & 63, wave = threadIdx.x >> 6;
  int row16 = lane & 15, grp = lane >> 4;
  int rt = wave >> 2, jseg = wave & 3;
  int r0 = blockIdx.x * 64;
  int rbase = r0 + rt * 32;
  float RL = Rf[h * NN + rbase + row16];
  float RH = Rf[h * NN + rbase + 16 + row16];
  _Float16 rl = (_Float16)RL, rh = (_Float16)RH;
  f16x2 RhL = {rl, rl}, RhH = {rh, rh};

  H8 ones;
#pragma unroll
  for (int k = 0; k < 4; ++k) ones.u[k] = 0x3C003C00u;   // fp16 1.0 pairs

  const unsigned short* wsrc =
      Whfrag + (size_t)h * 262144 + (size_t)jseg * 32 * 2048 + lane * 8;
  const unsigned short* esrc =
      ((lane & 4) ? E2h : E1h) + h * NN + jseg * 1024 + (lane & 3) * 8;
  const unsigned* asrc = adjbitsT + (size_t)(jseg * 32) * NN + r0 + lane;

  f32x4 l0 = {0,0,0,0}, l1 = {0,0,0,0}, l2 = {0,0,0,0}, ld = {0,0,0,0}, lden = {0,0,0,0};
  f32x4 h0 = {0,0,0,0}, h1 = {0,0,0,0}, h2 = {0,0,0,0}, hd = {0,0,0,0}, hden = {0,0,0,0};

  char* seg0 = lds + (jseg * 2 + 0) * SEGB;
  char* seg1 = lds + (jseg * 2 + 1) * SEGB;

  auto stage = [&](char* seg, int p) {     // stage tile (jseg*32+p): rt0=B, rt1=adj+E
    if (rt == 0) {
      const unsigned short* bs = wsrc + (size_t)p * 2048;
      GLOAD_LDS16(bs, seg);
      GLOAD_LDS16(bs + 512, seg + 1024);
      GLOAD_LDS16(bs + 1024, seg + 2048);
      GLOAD_LDS16(bs + 1536, seg + 3072);
    } else {
      GLOAD_LDS4(asrc + (size_t)p * NN, seg + A_OFF);          // 64 rows of adj bits
      if (lane < 8) GLOAD_LDS16(esrc + p * 32, seg + E_OFF);   // e1 | e2, halved
    }
  };

  auto compute = [&](const char* seg) {
    unsigned bwL = *(const unsigned*)(seg + A_OFF + (rt * 32 + row16) * 4);
    unsigned bwH = *(const unsigned*)(seg + A_OFF + (rt * 32 + 16 + row16) * 4);
    unsigned bbL = (bwL >> (grp * 8)) & 0xffu;
    unsigned bbH = (bwH >> (grp * 8)) & 0xffu;
    unsigned tL = bbL | (bbL << 15);       // bit k at {k, k+15}
    unsigned tH = bbH | (bbH << 15);
    H8 e1, e2;
    e1.v = *(const f16x8*)(seg + E_OFF + grp * 16);
    e2.v = *(const f16x8*)(seg + E_OFF + 64 + grp * 16);
    const char* bp = seg + lane * 16;
    f16x8 b0 = *(const f16x8*)(bp);
    f16x8 b1 = *(const f16x8*)(bp + 1024);
    f16x8 b2 = *(const f16x8*)(bp + 2048);
    f16x8 b3 = *(const f16x8*)(bp + 3072);
    H8 afL, afH;
#pragma unroll
    for (int k = 0; k < 4; ++k) {
      f16x2 mxL = __builtin_elementwise_max(e1.p[k], RhL * e2.p[k]);
      f16x2 mxH = __builtin_elementwise_max(e1.p[k], RhH * e2.p[k]);
      U2 mL, mH;                           // halves: bit2k->pos14, bit2k+1->pos30 (fp16 2.0)
      mL.u = (tL << (14 - 2 * k)) & 0x40004000u;
      mH.u = (tH << (14 - 2 * k)) & 0x40004000u;
      afL.p[k] = mxL * mL.v;
      afH.p[k] = mxH * mH.v;
    }
    l0   = __builtin_amdgcn_mfma_f32_16x16x32_f16(afL.v, b0, l0, 0, 0, 0);
    l1   = __builtin_amdgcn_mfma_f32_16x16x32_f16(afL.v, b1, l1, 0, 0, 0);
    l2   = __builtin_amdgcn_mfma_f32_16x16x32_f16(afL.v, b2, l2, 0, 0, 0);
    ld   = __builtin_amdgcn_mfma_f32_16x16x32_f16(afL.v, b3, ld, 0, 0, 0);
    lden = __builtin_amdgcn_mfma_f32_16x16x32_f16(afL.v, ones.v, lden, 0, 0, 0);
    h0   = __builtin_amdgcn_mfma_f32_16x16x32_f16(afH.v, b0, h0, 0, 0, 0);
    h1   = __builtin_amdgcn_mfma_f32_16x16x32_f16(afH.v, b1, h1, 0, 0, 0);
    h2   = __builtin_amdgcn_mfma_f32_16x16x32_f16(afH.v, b2, h2, 0, 0, 0);
    hd   = __builtin_amdgcn_mfma_f32_16x16x32_f16(afH.v, b3, hd, 0, 0, 0);
    hden = __builtin_amdgcn_mfma_f32_16x16x32_f16(afH.v, ones.v, hden, 0, 0, 0);
  };

  stage(seg0, 0);
  __syncthreads();
#pragma unroll 1
  for (int p2 = 0; p2 < 16; ++p2) {
    stage(seg1, 2 * p2 + 1);
    compute(seg0);
    __syncthreads();
    if (p2 < 15) stage(seg0, 2 * p2 + 2);
    compute(seg1);
    __syncthreads();
  }

  // ---- cross-jseg reduction (61440 B overlay) + normalize + store ----
  float* red = (float*)lds;
  if (jseg != 0) {
    float* q = red + (((jseg - 1) * 2 + rt) * 64 + lane) * 40;
    *(f32x4*)(q +  0) = l0;  *(f32x4*)(q +  4) = l1;
    *(f32x4*)(q +  8) = l2;  *(f32x4*)(q + 12) = ld;
    *(f32x4*)(q + 16) = lden;
    *(f32x4*)(q + 20) = h0;  *(f32x4*)(q + 24) = h1;
    *(f32x4*)(q + 28) = h2;  *(f32x4*)(q + 32) = hd;
    *(f32x4*)(q + 36) = hden;
  }
  __syncthreads();
  if (jseg == 0) {
#pragma unroll
    for (int s = 0; s < 3; ++s) {
      const float* q = red + ((s * 2 + rt) * 64 + lane) * 40;
      l0   += *(const f32x4*)(q +  0);  l1   += *(const f32x4*)(q +  4);
      l2   += *(const f32x4*)(q +  8);  ld   += *(const f32x4*)(q + 12);
      lden += *(const f32x4*)(q + 16);
      h0   += *(const f32x4*)(q + 20);  h1   += *(const f32x4*)(q + 24);
      h2   += *(const f32x4*)(q + 28);  hd   += *(const f32x4*)(q + 32);
      hden += *(const f32x4*)(q + 36);
    }
#pragma unroll
    for (int reg = 0; reg < 4; ++reg) {
      float invL = 1.0f / lden[reg];
      float invH = 1.0f / hden[reg];
      int rowL = rbase + grp * 4 + reg;
      int rowH = rbase + 16 + grp * 4 + reg;
      float* opL = out + (size_t)rowL * (NH * FO) + h * FO + row16;
      float* opH = out + (size_t)rowH * (NH * FO) + h * FO + row16;
      opL[0]  = l0[reg] * invL;  opL[16] = l1[reg] * invL;
      opL[32] = l2[reg] * invL;  opL[48] = ld[reg] * invL;
      opH[0]  = h0[reg] * invH;  opH[16] = h1[reg] * invH;
      opH[32] = h2[reg] * invH;  opH[48] = hd[reg] * invH;
    }
  }
}

extern "C" void kernel_launch(void* const* d_in, const int* in_sizes, int n_in,
                              void* d_out, int out_size, void* d_ws, size_t ws_size,
                              hipStream_t stream) {
  const float* X  = (const float*)d_in[0];
  const int* adj  = (const int*)d_in[1];
  const float* W  = (const float*)d_in[2];
  const float* a  = (const float*)d_in[3];
  float* out = (float*)d_out;
  char* ws = (char*)d_ws;

  unsigned short* Xh     = (unsigned short*)(ws + 0);          // 4 MB
  unsigned short* WbT    = (unsigned short*)(ws + 4194304);    // 512 KB
  unsigned* adjbitsT     = (unsigned*)(ws + 4718592);          // 2 MB
  unsigned short* Whfrag = (unsigned short*)(ws + 6815744);    // 4 MB
  unsigned short* WAh    = (unsigned short*)(ws + 11010048);   // 16 KB
  float* Rf              = (float*)(ws + 11026432);            // 128 KB
  unsigned short* E1h    = (unsigned short*)(ws + 11288576);   // 64 KB
  unsigned short* E2h    = (unsigned short*)(ws + 11354112);   // 64 KB (total ~11.4 MB)

  prep_kernel<<<5152, 256, 0, stream>>>(X, adj, W, a, Xh, WbT, adjbitsT, WAh);
  proj_sd_kernel<<<544, 512, 0, stream>>>(Xh, WbT, WAh, Whfrag, Rf, E1h, E2h);
  gat_kernel<<<dim3(64, 8), 512, 0, stream>>>(adjbitsT, Whfrag, Rf, E1h, E2h, out);
}